// Round 17
// baseline (61.868 us; speedup 1.0000x reference)
//
#include <hip/hip_runtime.h>
#include <stdint.h>

#define LL    2000
#define NB    512
#define CIN   32
#define COUT  32
#define LPAD  2048   // padded pair-stride per n (16 KB rows)

typedef float f32x4 __attribute__((ext_vector_type(4)));

// tap value = popc(t1) - 2*popc(t2); accumulate P,Q
#define TAP(nzx, snx, wz, ws) \
    { uint32_t t1 = (nzx) & (wz); uint32_t t2 = ((snx) ^ (ws)) & t1; \
      P += __popc(t1); Q += __popc(t2); }

// ---------------- kernel A: pack x signs (read-stream) ------------------------
// xb[n] row of uint2 pairs: pair index p+1 <-> position p; index 0 and LL+1 are
// zero boundary pairs. Block = (n, quarter); thread t<250 packs 2 positions.
__global__ __launch_bounds__(256, 8) void pack_x_kernel(const float* __restrict__ x,
                                                        uint32_t* __restrict__ xb) {
    const int n    = blockIdx.y;
    const int t    = threadIdx.x;
    if (t >= 250) return;
    const int p2   = blockIdx.x * 250 + t;     // 0..999
    const int l    = 2 * p2;
    const float* xn = x + (size_t)n * (CIN * LL) + l;

    uint32_t nz0 = 0, sn0 = 0, nz1 = 0, sn1 = 0;
    #pragma unroll
    for (int ci = 0; ci < CIN; ++ci) {
        const float2 v = *(const float2*)(xn + (size_t)ci * LL);
        const uint32_t ux = __float_as_uint(v.x), uy = __float_as_uint(v.y);
        const uint32_t nx = (ux << 1) ? 1u : 0u;   // != +-0
        const uint32_t ny = (uy << 1) ? 1u : 0u;
        nz0 |= nx << ci;  sn0 |= ((ux >> 31) & nx) << ci;
        nz1 |= ny << ci;  sn1 |= ((uy >> 31) & ny) << ci;
    }
    uint32_t* row = xb + (size_t)n * (LPAD * 2);
    *(uint2*)(row + 2 * (l + 1)) = make_uint2(nz0, sn0);
    *(uint2*)(row + 2 * (l + 2)) = make_uint2(nz1, sn1);
    if (p2 == 0)   *(uint2*)(row)                = make_uint2(0u, 0u);  // pos -1
    if (p2 == 999) *(uint2*)(row + 2 * (LL + 1)) = make_uint2(0u, 0u);  // pos LL
}

// ---------------- kernel B: ternary conv (write-stream) -----------------------
// Block = (n, half); thread t<250 computes 4 positions x 32 co. Packed reads are
// L2/L3-hot (8.4 MB total); weights/o_scale staged in LDS per block (r14-proven).
__global__ __launch_bounds__(256, 4) void conv_kernel(const uint32_t* __restrict__ xb,
                                                      const float* __restrict__ w,
                                                      const float* __restrict__ osc,
                                                      const float* __restrict__ lsc,
                                                      float* __restrict__ out) {
    __shared__ uint32_t wlds[256];   // wlds[co*8 + k*2 + {nz,sn}]
    __shared__ float    olds[COUT];

    const int t = threadIdx.x;
    if (t < COUT) olds[t] = osc[t];
    if (t < COUT * 3) {
        const int co = t / 3, k = t % 3;
        uint32_t nz = 0, sn = 0;
        #pragma unroll
        for (int ci = 0; ci < CIN; ++ci) {
            const float vw = w[(co * CIN + ci) * 3 + k];
            nz |= ((uint32_t)(vw != 0.0f)) << ci;
            sn |= ((uint32_t)(vw <  0.0f)) << ci;
        }
        wlds[co * 8 + k * 2]     = nz;
        wlds[co * 8 + k * 2 + 1] = sn;
    }
    __syncthreads();
    if (t >= 250) return;

    const int n  = blockIdx.y;
    const int qd = blockIdx.x * 250 + t;       // 0..499
    const int l  = 4 * qd;
    // pairs (l-1..l+4) live at indices l..l+5 = words 8qd..8qd+11 (16B aligned)
    const uint32_t* row = xb + (size_t)n * (LPAD * 2) + 8 * qd;
    const uint4 A  = *(const uint4*)(row);       // (nz,sn)@l-1, @l
    const uint4 Bm = *(const uint4*)(row + 4);   // @l+1, @l+2
    const uint4 Cm = *(const uint4*)(row + 8);   // @l+3, @l+4
    const float4 ls = *(const float4*)(lsc + l);
    float* o = out + (size_t)n * (COUT * LL) + l;

    #pragma unroll 8
    for (int co = 0; co < COUT; ++co) {
        const uint32_t wz0 = wlds[co*8+0], ws0 = wlds[co*8+1];
        const uint32_t wz1 = wlds[co*8+2], ws1 = wlds[co*8+3];
        const uint32_t wz2 = wlds[co*8+4], ws2 = wlds[co*8+5];
        const float os = olds[co];

        int P = 0, Q = 0;
        TAP(A.x, A.y, wz0, ws0) TAP(A.z, A.w, wz1, ws1) TAP(Bm.x, Bm.y, wz2, ws2)
        const int d0 = P - 2 * Q;
        P = 0; Q = 0;
        TAP(A.z, A.w, wz0, ws0) TAP(Bm.x, Bm.y, wz1, ws1) TAP(Bm.z, Bm.w, wz2, ws2)
        const int d1 = P - 2 * Q;
        P = 0; Q = 0;
        TAP(Bm.x, Bm.y, wz0, ws0) TAP(Bm.z, Bm.w, wz1, ws1) TAP(Cm.x, Cm.y, wz2, ws2)
        const int d2 = P - 2 * Q;
        P = 0; Q = 0;
        TAP(Bm.z, Bm.w, wz0, ws0) TAP(Cm.x, Cm.y, wz1, ws1) TAP(Cm.z, Cm.w, wz2, ws2)
        const int d3 = P - 2 * Q;

        f32x4 r;
        r.x = (float)d0 * os * ls.x;
        r.y = (float)d1 * os * ls.y;
        r.z = (float)d2 * os * ls.z;
        r.w = (float)d3 * os * ls.w;
        __builtin_nontemporal_store(r, (f32x4*)(o + (size_t)co * LL));
    }
}

extern "C" void kernel_launch(void* const* d_in, const int* in_sizes, int n_in,
                              void* d_out, int out_size, void* d_ws, size_t ws_size,
                              hipStream_t stream) {
    const float* x   = (const float*)d_in[0];
    const float* w   = (const float*)d_in[1];
    const float* osc = (const float*)d_in[2];
    const float* lsc = (const float*)d_in[3];
    float* out = (float*)d_out;

    uint32_t* xb = (uint32_t*)d_ws;   // 512 * 2048 * 8 B = 8.4 MB

    pack_x_kernel<<<dim3(4, NB), 256, 0, stream>>>(x, xb);
    conv_kernel  <<<dim3(2, NB), 256, 0, stream>>>(xb, w, osc, lsc, out);
}

// Round 18
// 52.608 us; speedup vs baseline: 1.1760x; 1.1760x over previous
//
#include <hip/hip_runtime.h>
#include <stdint.h>

#define LL    2000
#define NB    512
#define CIN   32
#define COUT  32
#define TILE  256
#define NTILE 4        // tiles per block
#define NH    2        // halves per n -> grid = NB*NH = 1024 = 4 blocks/CU exactly

typedef float f32x4 __attribute__((ext_vector_type(4)));

// ---------------- kernel 1: pack weight ternary masks ------------------------
__global__ __launch_bounds__(96) void pack_w_kernel(const float* __restrict__ w,
                                                    uint32_t* __restrict__ wb) {
    int t = threadIdx.x;
    if (t >= COUT * 3) return;
    int co = t / 3, k = t % 3;
    uint32_t nz = 0, sn = 0;
    #pragma unroll
    for (int ci = 0; ci < CIN; ++ci) {
        float v = w[(co * CIN + ci) * 3 + k];
        nz |= ((uint32_t)(v != 0.0f)) << ci;
        sn |= ((uint32_t)(v < 0.0f)) << ci;
    }
    wb[co * 8 + k * 2 + 0] = nz;
    wb[co * 8 + k * 2 + 1] = sn;
}

#define TAP(nzx, snx, wz, ws) \
    { uint32_t t1 = (nzx) & (wz); uint32_t t2 = ((snx) ^ (ws)) & t1; \
      P += __popc(t1); Q += __popc(t2); }

#define PK(vv, jj) { const uint32_t m = bit0 << (jj); \
    if ((vv).x != 0.0f) nz0 |= m;   if ((vv).x < 0.0f) sn0 |= m; \
    if ((vv).y != 0.0f) nz1 |= m;   if ((vv).y < 0.0f) sn1 |= m; \
    if ((vv).z != 0.0f) nz2 |= m;   if ((vv).z < 0.0f) sn2 |= m; \
    if ((vv).w != 0.0f) nz3 |= m;   if ((vv).w < 0.0f) sn3 |= m; }

// issue next tile's loads (asm burst, guaranteed in flight across conv) + halo
#define ISSUE(TT) { \
    const int l0i = (h * NTILE + (TT)) * TILE; \
    const int lb  = l0i + 4 * q; \
    pvld = (lb < LL); \
    const int la = pvld ? lb : (LL - 4); \
    const uint32_t base = (uint32_t)((8 * g * LL + la) * 4); \
    asm volatile("global_load_dwordx4 %0, %1, %2" : "=v"(v0) : "v"(base),          "s"(xn)); \
    asm volatile("global_load_dwordx4 %0, %1, %2" : "=v"(v1) : "v"(base + 1u*LL*4), "s"(xn)); \
    asm volatile("global_load_dwordx4 %0, %1, %2" : "=v"(v2) : "v"(base + 2u*LL*4), "s"(xn)); \
    asm volatile("global_load_dwordx4 %0, %1, %2" : "=v"(v3) : "v"(base + 3u*LL*4), "s"(xn)); \
    asm volatile("global_load_dwordx4 %0, %1, %2" : "=v"(v4) : "v"(base + 4u*LL*4), "s"(xn)); \
    asm volatile("global_load_dwordx4 %0, %1, %2" : "=v"(v5) : "v"(base + 5u*LL*4), "s"(xn)); \
    asm volatile("global_load_dwordx4 %0, %1, %2" : "=v"(v6) : "v"(base + 6u*LL*4), "s"(xn)); \
    asm volatile("global_load_dwordx4 %0, %1, %2" : "=v"(v7) : "v"(base + 7u*LL*4), "s"(xn)); \
    if (t < 64) { \
        const int hc = (t < 32) ? (l0i - 1) : (l0i + TILE); \
        hv = (hc >= 0) && (hc < LL); \
        hu = __float_as_uint(xn[(size_t)(t & 31) * LL + (hv ? hc : 0)]); \
    } }

// wait burst (leave stores in flight unless FIRST), pack bits, halo, combine->fin[FB]
#define PACKC(FIRST, FB) { \
    if (FIRST) { asm volatile("s_waitcnt vmcnt(0)" : "+v"(v0), "+v"(v1), "+v"(v2), "+v"(v3), \
                              "+v"(v4), "+v"(v5), "+v"(v6), "+v"(v7) :: "memory"); } \
    else       { asm volatile("s_waitcnt vmcnt(8)" : "+v"(v0), "+v"(v1), "+v"(v2), "+v"(v3), \
                              "+v"(v4), "+v"(v5), "+v"(v6), "+v"(v7) :: "memory"); } \
    __builtin_amdgcn_sched_barrier(0); \
    uint32_t nz0=0,sn0=0,nz1=0,sn1=0,nz2=0,sn2=0,nz3=0,sn3=0; \
    PK(v0,0) PK(v1,1) PK(v2,2) PK(v3,3) PK(v4,4) PK(v5,5) PK(v6,6) PK(v7,7) \
    const uint32_t vm = pvld ? 0xFFFFFFFFu : 0u; \
    nz0 &= vm; sn0 &= vm; nz1 &= vm; sn1 &= vm; \
    nz2 &= vm; sn2 &= vm; nz3 &= vm; sn3 &= vm; \
    { uint32_t* dst = &grp[g][2 * (4 * q + 1)]; \
      *(uint2*)(dst + 0) = make_uint2(nz0, sn0); \
      *(uint2*)(dst + 2) = make_uint2(nz1, sn1); \
      *(uint2*)(dst + 4) = make_uint2(nz2, sn2); \
      *(uint2*)(dst + 6) = make_uint2(nz3, sn3); } \
    if (t < 64) { \
        const bool hnz = hv && ((hu << 1) != 0); \
        const bool hng = hnz && ((hu >> 31) != 0); \
        const unsigned long long bnz = __ballot(hnz); \
        const unsigned long long bng = __ballot(hng); \
        if (t == 0)  { fin[FB][0] = (uint32_t)bnz;  fin[FB][1] = (uint32_t)bng; } \
        if (t == 32) { fin[FB][2 * (TILE + 1)]     = (uint32_t)(bnz >> 32); \
                       fin[FB][2 * (TILE + 1) + 1] = (uint32_t)(bng >> 32); } } \
    __syncthreads(); \
    for (int i = t + 2; i < (TILE + 1) * 2; i += 256) \
        fin[FB][i] = grp[0][i] | grp[1][i] | grp[2][i] | grp[3][i]; \
    __syncthreads(); }

// ---------------- kernel 2: persistent 4-tile pipelined pack+conv -------------
__global__ __launch_bounds__(256, 4) void fused_kernel(const float* __restrict__ x,
                                                       const uint32_t* __restrict__ wb,
                                                       const float* __restrict__ osc,
                                                       const float* __restrict__ lsc,
                                                       float* __restrict__ out) {
    __shared__ uint32_t grp[4][(TILE + 2) * 2];   // 8256 B
    __shared__ uint32_t fin[2][(TILE + 2) * 2];   // 4128 B

    const int b = blockIdx.x;
    const int n = b >> 1;
    const int h = b & 1;
    const int t = threadIdx.x;
    const int g = __builtin_amdgcn_readfirstlane(t >> 6);
    const int q = t & 63;
    const uint32_t bit0 = 1u << (8 * g);
    const float* xn = x + (size_t)n * (CIN * LL);
    float* on = out + (size_t)n * (COUT * LL);

    f32x4 v0, v1, v2, v3, v4, v5, v6, v7;
    uint32_t hu = 0;
    bool hv = false, pvld = true;

    ISSUE(0)
    PACKC(true, 0)

    #pragma unroll 1
    for (int tt = 0; tt < NTILE; ++tt) {
        const int l0t = (h * NTILE + tt) * TILE;
        const int l   = l0t + 4 * q;
        const int lc  = (l < LL) ? l : 0;
        float4 lsv = *(const float4*)(lsc + lc);
        // force lsv materialized (waitcnt) BEFORE the next burst's asm
        asm volatile("" :: "v"(lsv.x), "v"(lsv.y), "v"(lsv.z), "v"(lsv.w));

        if (tt < NTILE - 1) ISSUE(tt + 1)

        // ---- conv tile tt from fin[tt&1]; stores overlap the in-flight burst
        {
            const uint32_t* fb = fin[tt & 1];
            const uint4 A = *(const uint4*)&fb[8 * q];
            const uint4 B = *(const uint4*)&fb[8 * q + 4];
            const uint4 C = *(const uint4*)&fb[8 * q + 8];
            if (l < LL) {
                float* o = on + l;
                #pragma unroll
                for (int j = 0; j < 8; ++j) {
                    const int co = 8 * g + j;
                    const uint32_t wz0 = wb[co*8+0], ws0 = wb[co*8+1];
                    const uint32_t wz1 = wb[co*8+2], ws1 = wb[co*8+3];
                    const uint32_t wz2 = wb[co*8+4], ws2 = wb[co*8+5];
                    const float os = osc[co];

                    int P = 0, Q = 0;
                    TAP(A.x, A.y, wz0, ws0) TAP(A.z, A.w, wz1, ws1) TAP(B.x, B.y, wz2, ws2)
                    const int d0 = P - 2 * Q;
                    P = 0; Q = 0;
                    TAP(A.z, A.w, wz0, ws0) TAP(B.x, B.y, wz1, ws1) TAP(B.z, B.w, wz2, ws2)
                    const int d1 = P - 2 * Q;
                    P = 0; Q = 0;
                    TAP(B.x, B.y, wz0, ws0) TAP(B.z, B.w, wz1, ws1) TAP(C.x, C.y, wz2, ws2)
                    const int d2 = P - 2 * Q;
                    P = 0; Q = 0;
                    TAP(B.z, B.w, wz0, ws0) TAP(C.x, C.y, wz1, ws1) TAP(C.z, C.w, wz2, ws2)
                    const int d3 = P - 2 * Q;

                    f32x4 r;
                    r.x = (float)d0 * os * lsv.x;
                    r.y = (float)d1 * os * lsv.y;
                    r.z = (float)d2 * os * lsv.z;
                    r.w = (float)d3 * os * lsv.w;
                    __builtin_nontemporal_store(r, (f32x4*)(o + (size_t)co * LL));
                }
            }
        }

        if (tt < NTILE - 1) PACKC(false, (tt + 1) & 1)
    }
}

extern "C" void kernel_launch(void* const* d_in, const int* in_sizes, int n_in,
                              void* d_out, int out_size, void* d_ws, size_t ws_size,
                              hipStream_t stream) {
    const float* x   = (const float*)d_in[0];
    const float* w   = (const float*)d_in[1];
    const float* osc = (const float*)d_in[2];
    const float* lsc = (const float*)d_in[3];
    float* out = (float*)d_out;

    uint32_t* wb = (uint32_t*)d_ws;   // 1 KiB used

    pack_w_kernel<<<1, 96, 0, stream>>>(w, wb);
    fused_kernel<<<NB * NH, 256, 0, stream>>>(x, wb, osc, lsc, out);
}